// Round 1
// baseline (210.572 us; speedup 1.0000x reference)
//
#include <hip/hip_runtime.h>
#include <hip/hip_bf16.h>

// NPairLoss on MI355X (gfx950).
// loss = mean_i [ log( sum_j exp(sim_ij) + e ) - pos_sim_i ] + 0.02*||examples||_F
// where sim_ij = <a_i/|a_i|, p_j/|p_j|>  (diag-replacement cancels against pos logit).

#define NR 8192
#define DD 512

typedef __attribute__((ext_vector_type(8))) short bf16x8_t;
typedef __attribute__((ext_vector_type(4))) float f32x4_t;

__device__ __forceinline__ ushort f2bf(float x) {
    __hip_bfloat16 h = __float2bfloat16(x);
    return *reinterpret_cast<ushort*>(&h);
}

// ---------------- prep: normalize rows -> bf16, pos_sim, norm2, zero rowsum ---
__global__ __launch_bounds__(128) void prep_kernel(
    const float* __restrict__ ex,
    ushort* __restrict__ Ah, ushort* __restrict__ Ph,
    float* __restrict__ pos_sim, float* __restrict__ norm2,
    float* __restrict__ rowsum)
{
    const int i = blockIdx.x;
    const int t = threadIdx.x;            // 0..127, 4 floats each
    const float4 a = ((const float4*)(ex + (size_t)i * 1024))[t];
    const float4 p = ((const float4*)(ex + (size_t)i * 1024 + 512))[t];
    float sa  = a.x*a.x + a.y*a.y + a.z*a.z + a.w*a.w;
    float sp  = p.x*p.x + p.y*p.y + p.z*p.z + p.w*p.w;
    float sap = a.x*p.x + a.y*p.y + a.z*p.z + a.w*p.w;
    #pragma unroll
    for (int m = 1; m < 64; m <<= 1) {
        sa  += __shfl_xor(sa,  m, 64);
        sp  += __shfl_xor(sp,  m, 64);
        sap += __shfl_xor(sap, m, 64);
    }
    __shared__ float red[3][2];
    if ((t & 63) == 0) { red[0][t>>6] = sa; red[1][t>>6] = sp; red[2][t>>6] = sap; }
    __syncthreads();
    sa  = red[0][0] + red[0][1];
    sp  = red[1][0] + red[1][1];
    sap = red[2][0] + red[2][1];
    const float inva = rsqrtf(sa);
    const float invp = rsqrtf(sp);
    ushort4 av, pv;
    av.x = f2bf(a.x * inva); av.y = f2bf(a.y * inva);
    av.z = f2bf(a.z * inva); av.w = f2bf(a.w * inva);
    pv.x = f2bf(p.x * invp); pv.y = f2bf(p.y * invp);
    pv.z = f2bf(p.z * invp); pv.w = f2bf(p.w * invp);
    ((ushort4*)(Ah + (size_t)i * DD))[t] = av;
    ((ushort4*)(Ph + (size_t)i * DD))[t] = pv;
    if (t == 0) {
        pos_sim[i] = sap * inva * invp;
        norm2[i]   = sa + sp;
        rowsum[i]  = 0.0f;
    }
}

// ---------------- GEMM + exp-rowsum (flash-style, no max needed: |sim|<=1) ---
__global__ __launch_bounds__(256) void gemm_kernel(
    const ushort* __restrict__ Ah, const ushort* __restrict__ Ph,
    float* __restrict__ rowsum)
{
    __shared__ ushort lsA[128 * 32];   // [row][k] row-major, 64B rows
    __shared__ ushort lsB[128 * 32];
    const int t  = threadIdx.x;
    const int w  = t >> 6;             // wave 0..3
    const int l  = t & 63;
    const int m0 = blockIdx.y * 128;
    const int n0 = blockIdx.x * 128;

    f32x4_t acc[4][4];
    #pragma unroll
    for (int i = 0; i < 4; i++)
        #pragma unroll
        for (int j = 0; j < 4; j++)
            acc[i][j] = (f32x4_t){0.f, 0.f, 0.f, 0.f};

    const int wr = w >> 1, wc = w & 1;
    const int lh = l >> 4;             // k-group 0..3
    const int ll = l & 15;             // fragment row/col
    const int srow = l >> 2;           // staging: row within 16-row chunk
    const int scol = (l & 3) * 16;     // staging: byte col within 64B row

    const char* Abase = (const char*)Ah;
    const char* Bbase = (const char*)Ph;

    for (int k0 = 0; k0 < DD; k0 += 32) {
        __syncthreads();
        #pragma unroll
        for (int r = 0; r < 2; ++r) {
            const int rowA = (r * 4 + w) * 16 + srow;
            const char* ga = Abase + (size_t)(m0 + rowA) * (DD * 2) + (size_t)k0 * 2 + scol;
            const char* gb = Bbase + (size_t)(n0 + rowA) * (DD * 2) + (size_t)k0 * 2 + scol;
            __builtin_amdgcn_global_load_lds(
                (const __attribute__((address_space(1))) void*)ga,
                (__attribute__((address_space(3))) void*)(&lsA[(r * 4 + w) * 512]),
                16, 0, 0);
            __builtin_amdgcn_global_load_lds(
                (const __attribute__((address_space(1))) void*)gb,
                (__attribute__((address_space(3))) void*)(&lsB[(r * 4 + w) * 512]),
                16, 0, 0);
        }
        __syncthreads();
        bf16x8_t af[4], bfr[4];
        #pragma unroll
        for (int mi = 0; mi < 4; mi++)
            af[mi] = *(const bf16x8_t*)&lsA[(wr * 64 + mi * 16 + ll) * 32 + lh * 8];
        #pragma unroll
        for (int ni = 0; ni < 4; ni++)
            bfr[ni] = *(const bf16x8_t*)&lsB[(wc * 64 + ni * 16 + ll) * 32 + lh * 8];
        #pragma unroll
        for (int mi = 0; mi < 4; mi++)
            #pragma unroll
            for (int ni = 0; ni < 4; ni++)
                acc[mi][ni] = __builtin_amdgcn_mfma_f32_16x16x32_bf16(
                    af[mi], bfr[ni], acc[mi][ni], 0, 0, 0);
    }

    // epilogue: per-row sum of exp over this block's 128 cols, then atomicAdd.
    // C/D layout: col = n0 + wc*64 + ni*16 + ll ; row = m0 + wr*64 + mi*16 + lh*4 + r
    #pragma unroll
    for (int mi = 0; mi < 4; mi++) {
        #pragma unroll
        for (int r = 0; r < 4; r++) {
            float s = __expf(acc[mi][0][r]) + __expf(acc[mi][1][r]) +
                      __expf(acc[mi][2][r]) + __expf(acc[mi][3][r]);
            #pragma unroll
            for (int m = 1; m < 16; m <<= 1) s += __shfl_xor(s, m, 64);
            if (ll == 0)
                atomicAdd(&rowsum[m0 + wr * 64 + mi * 16 + lh * 4 + r], s);
        }
    }
}

// ---------------- final reduce -----------------------------------------------
__global__ __launch_bounds__(256) void final_kernel(
    const float* __restrict__ rowsum, const float* __restrict__ pos_sim,
    const float* __restrict__ norm2, float* __restrict__ out)
{
    const int t = threadIdx.x;
    float s1 = 0.f, s2 = 0.f;
    for (int i = t; i < NR; i += 256) {
        s1 += logf(rowsum[i] + 2.71828182845904523536f) - pos_sim[i];
        s2 += norm2[i];
    }
    #pragma unroll
    for (int m = 1; m < 64; m <<= 1) {
        s1 += __shfl_xor(s1, m, 64);
        s2 += __shfl_xor(s2, m, 64);
    }
    __shared__ float r1[4], r2[4];
    if ((t & 63) == 0) { r1[t>>6] = s1; r2[t>>6] = s2; }
    __syncthreads();
    if (t == 0) {
        float a = r1[0] + r1[1] + r1[2] + r1[3];
        float b = r2[0] + r2[1] + r2[2] + r2[3];
        out[0] = a / (float)NR + 0.02f * sqrtf(b);
    }
}

extern "C" void kernel_launch(void* const* d_in, const int* in_sizes, int n_in,
                              void* d_out, int out_size, void* d_ws, size_t ws_size,
                              hipStream_t stream) {
    const float* ex = (const float*)d_in[0];
    float* out = (float*)d_out;
    char* ws = (char*)d_ws;
    ushort* Ah     = (ushort*)(ws);                         // 8 MiB
    ushort* Ph     = (ushort*)(ws + 8388608);               // 8 MiB
    float*  possim = (float*)(ws + 16777216);               // 32 KiB
    float*  norm2  = (float*)(ws + 16777216 + 32768);       // 32 KiB
    float*  rowsum = (float*)(ws + 16777216 + 65536);       // 32 KiB

    prep_kernel<<<NR, 128, 0, stream>>>(ex, Ah, Ph, possim, norm2, rowsum);
    gemm_kernel<<<dim3(NR / 128, NR / 128), 256, 0, stream>>>(Ah, Ph, rowsum);
    final_kernel<<<1, 256, 0, stream>>>(rowsum, possim, norm2, out);
}

// Round 2
// 207.102 us; speedup vs baseline: 1.0168x; 1.0168x over previous
//
#include <hip/hip_runtime.h>
#include <hip/hip_bf16.h>

// NPairLoss on MI355X (gfx950).
// loss = mean_i [ log( rowsum_i + e ) - pos_sim_i ] + 0.02*||examples||_F
// rowsum_i = sum_j exp(sim_ij), sim = (A/|A|)·(P/|P|)^T ; diag-replacement -> +e.
//
// GEMM: 256x256 tile, BK=64, 8 waves (2Mx4N), double-buffered LDS (128 KiB),
// 2-phase schedule (stage next while computing current), both-sides XOR swizzle
// (pre-swizzled global_load_lds source + swizzled ds_read) -> conflict-free b128.

#define NR 8192
#define DD 512
#define E_CONST 2.71828182845904523536f

typedef __attribute__((ext_vector_type(8))) short bf16x8_t;
typedef __attribute__((ext_vector_type(4))) float f32x4_t;

__device__ __forceinline__ ushort f2bf(float x) {
    __hip_bfloat16 h = __float2bfloat16(x);
    return *reinterpret_cast<ushort*>(&h);
}

// ---------------- prep: normalize rows -> bf16, pos_sim, norm2, zero accums ---
__global__ __launch_bounds__(128) void prep_kernel(
    const float* __restrict__ ex,
    ushort* __restrict__ Ah, ushort* __restrict__ Ph,
    float* __restrict__ pos_sim, float* __restrict__ norm2,
    float* __restrict__ rowsum, float* __restrict__ part)
{
    const int i = blockIdx.x;
    const int t = threadIdx.x;            // 0..127, 4 floats each
    const float4 a = ((const float4*)(ex + (size_t)i * 1024))[t];
    const float4 p = ((const float4*)(ex + (size_t)i * 1024 + 512))[t];
    float sa  = a.x*a.x + a.y*a.y + a.z*a.z + a.w*a.w;
    float sp  = p.x*p.x + p.y*p.y + p.z*p.z + p.w*p.w;
    float sap = a.x*p.x + a.y*p.y + a.z*p.z + a.w*p.w;
    #pragma unroll
    for (int m = 1; m < 64; m <<= 1) {
        sa  += __shfl_xor(sa,  m, 64);
        sp  += __shfl_xor(sp,  m, 64);
        sap += __shfl_xor(sap, m, 64);
    }
    __shared__ float red[3][2];
    if ((t & 63) == 0) { red[0][t>>6] = sa; red[1][t>>6] = sp; red[2][t>>6] = sap; }
    __syncthreads();
    sa  = red[0][0] + red[0][1];
    sp  = red[1][0] + red[1][1];
    sap = red[2][0] + red[2][1];
    const float inva = rsqrtf(sa);
    const float invp = rsqrtf(sp);
    ushort4 av, pv;
    av.x = f2bf(a.x * inva); av.y = f2bf(a.y * inva);
    av.z = f2bf(a.z * inva); av.w = f2bf(a.w * inva);
    pv.x = f2bf(p.x * invp); pv.y = f2bf(p.y * invp);
    pv.z = f2bf(p.z * invp); pv.w = f2bf(p.w * invp);
    ((ushort4*)(Ah + (size_t)i * DD))[t] = av;
    ((ushort4*)(Ph + (size_t)i * DD))[t] = pv;
    if (t == 0) {
        pos_sim[i] = sap * inva * invp;
        norm2[i]   = sa + sp;
        rowsum[i]  = 0.0f;
        if (i == 0) { part[0] = 0.0f; part[1] = 0.0f; }
    }
}

// ---------------- GEMM 256^2, BK=64, 8 waves, 2-phase dbuf -------------------
__global__ __launch_bounds__(512, 2) void gemm_kernel(
    const ushort* __restrict__ Ah, const ushort* __restrict__ Ph,
    float* __restrict__ rowsum)
{
    // ls layout: [buf(2)][mat(2: A,B)][256 rows][64 ushorts(=BK)] = 128 KiB
    __shared__ ushort ls[65536];
    const int t  = threadIdx.x;           // 0..511
    const int w  = t >> 6;                // wave 0..7
    const int l  = t & 63;
    const int wr = w >> 2, wc = w & 3;    // 2M x 4N wave grid
    const int ll = l & 15, lh = l >> 4;
    const int m0 = blockIdx.y * 256;
    const int n0 = blockIdx.x * 256;

    f32x4_t acc[8][4];
    #pragma unroll
    for (int i = 0; i < 8; i++)
        #pragma unroll
        for (int j = 0; j < 4; j++)
            acc[i][j] = (f32x4_t){0.f, 0.f, 0.f, 0.f};

    // staging geometry: thread t -> chunk-row (t>>3), 16B slot (t&7).
    // LDS dest is LINEAR (global_load_lds: wave base + lane*16); the bank
    // swizzle is applied by pre-swizzling the GLOBAL source slot (rule #21).
    const int srow  = t >> 3;                       // row within 64-row chunk
    const int gslot = (t & 7) ^ (srow & 7);         // pre-swizzled source slot

    auto stage = [&](int buf, int kt) {
        #pragma unroll
        for (int j = 0; j < 4; ++j) {
            const int row = j * 64 + srow;
            const char* ga = (const char*)Ah + (size_t)(m0 + row) * (DD * 2)
                             + kt * 128 + gslot * 16;
            const char* gb = (const char*)Ph + (size_t)(n0 + row) * (DD * 2)
                             + kt * 128 + gslot * 16;
            __builtin_amdgcn_global_load_lds(
                (const __attribute__((address_space(1))) void*)ga,
                (__attribute__((address_space(3))) void*)&ls[buf * 32768 + j * 4096 + t * 8],
                16, 0, 0);
            __builtin_amdgcn_global_load_lds(
                (const __attribute__((address_space(1))) void*)gb,
                (__attribute__((address_space(3))) void*)&ls[buf * 32768 + 16384 + j * 4096 + t * 8],
                16, 0, 0);
        }
    };

    // fragment read: row R, want k-slot s=ks*4+lh -> LDS slot s^(R&7)
    auto compute = [&](int buf) {
        const int aB = buf * 32768;
        const int bB = buf * 32768 + 16384;
        #pragma unroll
        for (int ks = 0; ks < 2; ++ks) {
            bf16x8_t af[8], bfv[4];
            #pragma unroll
            for (int mi = 0; mi < 8; ++mi) {
                const int R  = wr * 128 + mi * 16 + ll;
                const int ss = (ks * 4 + lh) ^ (R & 7);
                af[mi] = *(const bf16x8_t*)&ls[aB + R * 64 + ss * 8];
            }
            #pragma unroll
            for (int ni = 0; ni < 4; ++ni) {
                const int R  = wc * 64 + ni * 16 + ll;
                const int ss = (ks * 4 + lh) ^ (R & 7);
                bfv[ni] = *(const bf16x8_t*)&ls[bB + R * 64 + ss * 8];
            }
            __builtin_amdgcn_s_setprio(1);
            #pragma unroll
            for (int mi = 0; mi < 8; ++mi)
                #pragma unroll
                for (int ni = 0; ni < 4; ++ni)
                    acc[mi][ni] = __builtin_amdgcn_mfma_f32_16x16x32_bf16(
                        af[mi], bfv[ni], acc[mi][ni], 0, 0, 0);
            __builtin_amdgcn_s_setprio(0);
        }
    };

    // 2-phase: prologue stage, then {stage next | compute cur | barrier}
    stage(0, 0);
    __syncthreads();
    int cur = 0;
    #pragma unroll 1
    for (int kt = 0; kt < (DD / 64) - 1; ++kt) {
        stage(cur ^ 1, kt + 1);
        compute(cur);
        __syncthreads();          // drains vmcnt(0)+lgkmcnt(0): next tile ready
        cur ^= 1;
    }
    compute(cur);

    // epilogue: per-row sum of exp over this block's 256 cols -> atomicAdd.
    // C/D: col = n0 + wc*64 + ni*16 + (l&15); row = m0 + wr*128 + mi*16 + (l>>4)*4 + r
    #pragma unroll
    for (int mi = 0; mi < 8; ++mi) {
        #pragma unroll
        for (int r = 0; r < 4; ++r) {
            float s = __expf(acc[mi][0][r]) + __expf(acc[mi][1][r]) +
                      __expf(acc[mi][2][r]) + __expf(acc[mi][3][r]);
            s += __shfl_xor(s, 1, 64);
            s += __shfl_xor(s, 2, 64);
            s += __shfl_xor(s, 4, 64);
            s += __shfl_xor(s, 8, 64);
            if (ll == 0)
                atomicAdd(&rowsum[m0 + wr * 128 + mi * 16 + lh * 4 + r], s);
        }
    }
}

// ---------------- final reduce (parallel) -------------------------------------
__global__ __launch_bounds__(256) void final1_kernel(
    const float* __restrict__ rowsum, const float* __restrict__ pos_sim,
    const float* __restrict__ norm2, float* __restrict__ part)
{
    const int i = blockIdx.x * 256 + threadIdx.x;   // 32 blocks x 256 = 8192
    float s1 = logf(rowsum[i] + E_CONST) - pos_sim[i];
    float s2 = norm2[i];
    #pragma unroll
    for (int m = 1; m < 64; m <<= 1) {
        s1 += __shfl_xor(s1, m, 64);
        s2 += __shfl_xor(s2, m, 64);
    }
    if ((threadIdx.x & 63) == 0) {
        atomicAdd(&part[0], s1);
        atomicAdd(&part[1], s2);
    }
}

__global__ void final2_kernel(const float* __restrict__ part, float* __restrict__ out)
{
    out[0] = part[0] * (1.0f / NR) + 0.02f * sqrtf(part[1]);
}

extern "C" void kernel_launch(void* const* d_in, const int* in_sizes, int n_in,
                              void* d_out, int out_size, void* d_ws, size_t ws_size,
                              hipStream_t stream) {
    const float* ex = (const float*)d_in[0];
    float* out = (float*)d_out;
    char* ws = (char*)d_ws;
    ushort* Ah     = (ushort*)(ws);                         // 8 MiB
    ushort* Ph     = (ushort*)(ws + 8388608);               // 8 MiB
    float*  possim = (float*)(ws + 16777216);               // 32 KiB
    float*  norm2  = (float*)(ws + 16777216 + 32768);       // 32 KiB
    float*  rowsum = (float*)(ws + 16777216 + 65536);       // 32 KiB
    float*  part   = (float*)(ws + 16777216 + 98304);       // 8 B

    prep_kernel<<<NR, 128, 0, stream>>>(ex, Ah, Ph, possim, norm2, rowsum, part);
    gemm_kernel<<<dim3(NR / 256, NR / 256), 512, 0, stream>>>(Ah, Ph, rowsum);
    final1_kernel<<<NR / 256, 256, 0, stream>>>(rowsum, possim, norm2, part);
    final2_kernel<<<1, 1, 0, stream>>>(part, out);
}